// Round 2
// 661.863 us; speedup vs baseline: 1.0465x; 1.0465x over previous
//
#include <hip/hip_runtime.h>

// Greedy online bipartite matching decode.
// B=4096 rows, V=256 steps, U+1=129 options (col 0 = skip, weight 0).
// One wave64 per row; lane l owns cols l+1 and l+65. Steps 0..24 are
// provable no-ops (sel=0, weight 0, mask unchanged).
//
// This version: 8-deep row prefetch pipeline held in NAMED registers
// (macro slots q*_0..q*_7) so SROA can never demote it to scratch
// (rule #20: runtime-indexed arrays -> scratch -> hidden VMEM traffic).
// Step t=24 is processed as a forced-skip dummy so the 232 steps tile
// exactly into 29 blocks of 8; the last block is peeled with no
// prefetch (zero redundant tail loads).

template <int CTRL>
__device__ __forceinline__ float maxstep(float v) {
    float t = __int_as_float(__builtin_amdgcn_update_dpp(
        __float_as_int(v), __float_as_int(v), CTRL, 0xF, 0xF, false));
    return fmaxf(v, t);
}

// Full wave64 max broadcast to all lanes (uniform SGPR result).
__device__ __forceinline__ float wave_max_bcast(float v) {
    v = maxstep<0x111>(v);  // row_shr:1
    v = maxstep<0x112>(v);  // row_shr:2
    v = maxstep<0x114>(v);  // row_shr:4
    v = maxstep<0x118>(v);  // row_shr:8  -> lane15 of each 16-row has row max
    v = maxstep<0x142>(v);  // row_bcast:15
    v = maxstep<0x143>(v);  // row_bcast:31 -> lane 63 has wave max
    return __int_as_float(__builtin_amdgcn_readlane(__float_as_int(v), 63));
}

__global__ __launch_bounds__(256, 4) void greedy_match_kernel(
    const float* __restrict__ x,
    float* __restrict__ out,   // [B] = -size, then [B*V] = pi (as float)
    int B)
{
    const int V = 256;
    const int SKIP = 25;
    const int ROWLEN = 129;    // U+1
    const float NEG = -1e30f;

    int gtid = blockIdx.x * blockDim.x + threadIdx.x;
    int w = gtid >> 6;         // wave id = batch row
    int lane = gtid & 63;
    if (w >= B) return;

    const float* base = x + (size_t)w * V * ROWLEN;
    float* out_pi = out + B + (size_t)w * V;

    float acc = 0.0f;          // running matched weight (reference order)
    float pi_val = 0.0f;       // lanes 0..23 keep 0 => skip-phase pi correct
    unsigned int mask = 0;     // bit0: col lane+1 matched; bit1: col lane+65

    // ---- fill the 8-deep pipeline with rows 24..31 (named registers) ----
    float q0_0, q0_1, q0_2, q0_3, q0_4, q0_5, q0_6, q0_7;
    float q1_0, q1_1, q1_2, q1_3, q1_4, q1_5, q1_6, q1_7;
    {
        const float* r = base + (size_t)(SKIP - 1) * ROWLEN + 1 + lane;
#define FILL(U)                                                            \
        q0_##U = __builtin_nontemporal_load(r);                            \
        q1_##U = __builtin_nontemporal_load(r + 64);                       \
        r += ROWLEN;
        FILL(0) FILL(1) FILL(2) FILL(3) FILL(4) FILL(5) FILL(6) FILL(7)
#undef FILL
    }

#define STEP(U, TT, DOPF)                                                  \
    do {                                                                   \
        float nw0 = 0.0f, nw1 = 0.0f;                                      \
        if (DOPF) {                                                        \
            const float* pp =                                              \
                base + (size_t)((TT) + 8) * ROWLEN + 1 + lane;             \
            nw0 = __builtin_nontemporal_load(pp);                          \
            nw1 = __builtin_nontemporal_load(pp + 64);                     \
        }                                                                  \
        float a0 = (mask & 1u) ? NEG : q0_##U;                             \
        float a1 = (mask & 2u) ? NEG : q1_##U;                             \
        float m = fmaxf(fmaxf(a0, a1), 0.0f);  /* fold skip (weight 0) */  \
        if ((TT) < SKIP) m = 0.0f;             /* dummy step t=24 */       \
        float k = wave_max_bcast(m);           /* uniform, k >= 0 */       \
        int sel = 0;                                                       \
        if (k > 0.0f) {                        /* uniform branch */        \
            /* first-occurrence tie-break: cols 1..64 then 65..128 */      \
            unsigned long long b0 = __ballot(a0 == k);                     \
            unsigned long long b1 = __ballot(a1 == k);                     \
            sel = b0 ? __ffsll(b0) : (__ffsll(b1) + 64);                   \
        }                                                                  \
        acc += k;                              /* chosen weight (0=skip) */\
        if (sel == lane + 1)       mask |= 1u;                             \
        else if (sel == lane + 65) mask |= 2u;                             \
        if (lane == ((TT) & 63)) pi_val = (float)sel;                      \
        if (((TT) & 63) == 63) out_pi[((TT) & ~63) + lane] = pi_val;       \
        if (DOPF) { q0_##U = nw0; q1_##U = nw1; }                          \
    } while (0)

    // steps 24..247 : 28 blocks of 8, each step prefetches row t+8
    #pragma unroll 1
    for (int t = SKIP - 1; t < V - 8; t += 8) {
        STEP(0, t + 0, 1); STEP(1, t + 1, 1);
        STEP(2, t + 2, 1); STEP(3, t + 3, 1);
        STEP(4, t + 4, 1); STEP(5, t + 5, 1);
        STEP(6, t + 6, 1); STEP(7, t + 7, 1);
    }
    // steps 248..255 : peeled tail, no prefetch (literal TT -> folds)
    STEP(0, 248, 0); STEP(1, 249, 0); STEP(2, 250, 0); STEP(3, 251, 0);
    STEP(4, 252, 0); STEP(5, 253, 0); STEP(6, 254, 0); STEP(7, 255, 0);
#undef STEP

    if (lane == 0) out[w] = -acc;
}

extern "C" void kernel_launch(void* const* d_in, const int* in_sizes, int n_in,
                              void* d_out, int out_size, void* d_ws, size_t ws_size,
                              hipStream_t stream) {
    const float* x = (const float*)d_in[0];
    const int V = 256, ROWLEN = 129;
    int B = in_sizes[0] / (V * ROWLEN);   // 4096
    float* out = (float*)d_out;

    int threads = 256;                    // 4 waves per block
    int blocks = (B * 64 + threads - 1) / threads;
    greedy_match_kernel<<<blocks, threads, 0, stream>>>(x, out, B);
}

// Round 4
// 628.251 us; speedup vs baseline: 1.1024x; 1.0535x over previous
//
#include <hip/hip_runtime.h>

// Greedy online bipartite matching decode.
// B=4096 rows, V=256 steps, U+1=129 options (col 0 = skip, weight 0).
// One wave64 per row; lane l owns cols l+1 and l+65. Steps 0..24 are
// provable no-ops (sel=0, weight 0, mask unchanged).
//
// 8-deep row prefetch pipeline in NAMED registers (cannot be demoted to
// scratch). Step t=24 is a forced-skip dummy so 232 steps tile as 29x8.
//
// Early exit — once all 128 columns are matched (mask==3 in every
// lane), every remaining step is a forced skip (avail all NEG -> k=0,
// sel=0, acc+=0, pi=0). Detected once per 8-step block; the exit path
// flushes the partial pi block and zero-fills the rest. Typical rows
// exhaust columns by t~155 => ~40% of steps (and their loads) skipped.

template <int CTRL>
__device__ __forceinline__ float maxstep(float v) {
    float t = __int_as_float(__builtin_amdgcn_update_dpp(
        __float_as_int(v), __float_as_int(v), CTRL, 0xF, 0xF, false));
    return fmaxf(v, t);
}

// Full wave64 max broadcast to all lanes (uniform result).
__device__ __forceinline__ float wave_max_bcast(float v) {
    v = maxstep<0x111>(v);  // row_shr:1
    v = maxstep<0x112>(v);  // row_shr:2
    v = maxstep<0x114>(v);  // row_shr:4
    v = maxstep<0x118>(v);  // row_shr:8  -> lane15 of each 16-row has row max
    v = maxstep<0x142>(v);  // row_bcast:15
    v = maxstep<0x143>(v);  // row_bcast:31 -> lane 63 has wave max
    return __int_as_float(__builtin_amdgcn_readlane(__float_as_int(v), 63));
}

__global__ __launch_bounds__(256, 4) void greedy_match_kernel(
    const float* __restrict__ x,
    float* __restrict__ out,   // [B] = -size, then [B*V] = pi (as float)
    int B)
{
    const int V = 256;
    const int SKIP = 25;
    const int ROWLEN = 129;    // U+1
    const float NEG = -1e30f;

    int gtid = blockIdx.x * blockDim.x + threadIdx.x;
    int w = gtid >> 6;         // wave id = batch row
    int lane = gtid & 63;
    if (w >= B) return;

    const float* base = x + (size_t)w * V * ROWLEN;
    float* out_pi = out + B + (size_t)w * V;

    float acc = 0.0f;          // running matched weight (reference order)
    float pi_val = 0.0f;       // lanes 0..23 keep 0 => skip-phase pi correct
    unsigned int mask = 0;     // bit0: col lane+1 matched; bit1: col lane+65

    // ---- fill the 8-deep pipeline with rows 24..31 (named registers) ----
    float q0_0, q0_1, q0_2, q0_3, q0_4, q0_5, q0_6, q0_7;
    float q1_0, q1_1, q1_2, q1_3, q1_4, q1_5, q1_6, q1_7;
    {
        const float* r = base + (size_t)(SKIP - 1) * ROWLEN + 1 + lane;
#define FILL(U)                                                            \
        q0_##U = __builtin_nontemporal_load(r);                            \
        q1_##U = __builtin_nontemporal_load(r + 64);                       \
        r += ROWLEN;
        FILL(0) FILL(1) FILL(2) FILL(3) FILL(4) FILL(5) FILL(6) FILL(7)
#undef FILL
    }

#define STEP(U, TT, DOPF)                                                  \
    do {                                                                   \
        float nw0 = 0.0f, nw1 = 0.0f;                                      \
        if (DOPF) {                                                        \
            const float* pp =                                              \
                base + (size_t)((TT) + 8) * ROWLEN + 1 + lane;             \
            nw0 = __builtin_nontemporal_load(pp);                          \
            nw1 = __builtin_nontemporal_load(pp + 64);                     \
        }                                                                  \
        float a0 = (mask & 1u) ? NEG : q0_##U;                             \
        float a1 = (mask & 2u) ? NEG : q1_##U;                             \
        float m = fmaxf(fmaxf(a0, a1), 0.0f);  /* fold skip (weight 0) */  \
        if ((TT) < SKIP) m = 0.0f;             /* dummy step t=24 */       \
        float k = wave_max_bcast(m);           /* uniform, k >= 0 */       \
        int sel = 0;                                                       \
        if (k > 0.0f) {                        /* uniform branch */        \
            /* first-occurrence tie-break: cols 1..64 then 65..128 */      \
            unsigned long long b0 = __ballot(a0 == k);                     \
            unsigned long long b1 = __ballot(a1 == k);                     \
            sel = b0 ? __ffsll(b0) : (__ffsll(b1) + 64);                   \
        }                                                                  \
        acc += k;                              /* chosen weight (0=skip) */\
        if (sel == lane + 1)       mask |= 1u;                             \
        else if (sel == lane + 65) mask |= 2u;                             \
        if (lane == ((TT) & 63)) pi_val = (float)sel;                      \
        if (((TT) & 63) == 63) out_pi[((TT) & ~63) + lane] = pi_val;       \
        if (DOPF) { q0_##U = nw0; q1_##U = nw1; }                          \
    } while (0)

    // steps 24..247 : 28 blocks of 8, each step prefetches row t+8.
    // After each block, if all 128 columns are matched, the remaining
    // steps are provable forced skips -> exit early.
    int s_exit = -1;   // first unprocessed step if early exit
    #pragma unroll 1
    for (int t = SKIP - 1; t < V - 8; t += 8) {
        STEP(0, t + 0, 1); STEP(1, t + 1, 1);
        STEP(2, t + 2, 1); STEP(3, t + 3, 1);
        STEP(4, t + 4, 1); STEP(5, t + 5, 1);
        STEP(6, t + 6, 1); STEP(7, t + 7, 1);
        if (__all(mask == 3u)) { s_exit = t + 8; break; }
    }

    if (s_exit < 0) {
        // steps 248..255 : peeled tail, no prefetch (literal TT -> folds)
        STEP(0, 248, 0); STEP(1, 249, 0); STEP(2, 250, 0); STEP(3, 251, 0);
        STEP(4, 252, 0); STEP(5, 253, 0); STEP(6, 254, 0); STEP(7, 255, 0);
        if (lane == 0) out[w] = -acc;
        return;
    }
#undef STEP

    // ---- early-exit path: steps s_exit..255 are all forced skips ----
    // Flush the partial pi 64-block (zeros for lanes >= position), then
    // zero-store any remaining full blocks. acc is unchanged (k=0).
    {
        int p   = s_exit & 63;    // position within current 64-block
        int blk = s_exit & ~63;   // current 64-block base
        if (p > 0) {
            if (lane >= p) pi_val = 0.0f;
            out_pi[blk + lane] = pi_val;
            blk += 64;
        }
        for (; blk < V; blk += 64) out_pi[blk + lane] = 0.0f;
    }
    if (lane == 0) out[w] = -acc;
}

extern "C" void kernel_launch(void* const* d_in, const int* in_sizes, int n_in,
                              void* d_out, int out_size, void* d_ws, size_t ws_size,
                              hipStream_t stream) {
    const float* x = (const float*)d_in[0];
    const int V = 256, ROWLEN = 129;
    int B = in_sizes[0] / (V * ROWLEN);   // 4096
    float* out = (float*)d_out;

    int threads = 256;                    // 4 waves per block
    int blocks = (B * 64 + threads - 1) / threads;
    greedy_match_kernel<<<blocks, threads, 0, stream>>>(x, out, B);
}